// Round 9
// baseline (647.014 us; speedup 1.0000x reference)
//
#include <hip/hip_runtime.h>

// ---------------------------------------------------------------------------
// JointlyTrainModel round 22: fuse the 4 cheb launches into ONE kernel with
// the byte-identical R19 per-layer body (layer loop + __syncthreads between
// layers; R17 proved the block-local X-write -> barrier -> read path).
// R21 post-mortem: head1 swizzle was neutral (conflicts 9.9e6->8.9e6, dur
// 112.6 == R19's 113.4) -> conflicts never on head1's critical path; head1
// is latency-bound and resistant (3 attempts all 112-140). Keep R21 head1.
// The fused cheb removes 3 kernel-boundary drains (~10us each), 3 grid
// tails, and keeps each graph's x/X248 rows L2-hot across its 4 layers.
// Everything else byte-identical to R21.
// ---------------------------------------------------------------------------

#define NODES   62
#define BATCH   2048
#define NTOT    (NODES * BATCH)     // 126976
#define IN_DIM  128
#define OUT_DIM 62
#define ACOLS   248                 // 4*62 activation cols
#define FEAT    15376               // 62*248
#define LIN1    512
#define LIN2    256
#define NCLS    3
#define BN_EPS  1e-5f

typedef __attribute__((ext_vector_type(8)))  short  short8;
typedef __attribute__((ext_vector_type(4)))  float  f32x4;
typedef __attribute__((ext_vector_type(16))) float  f32x16;
typedef __attribute__((ext_vector_type(4)))  unsigned short us4;

__device__ inline unsigned short f2bf(float x) {   // RTNE
    unsigned u = __builtin_bit_cast(unsigned, x);
    return (unsigned short)((u + 0x7fffu + ((u >> 16) & 1u)) >> 16);
}
__device__ inline float bf2f(unsigned short h) {
    return __builtin_bit_cast(float, (unsigned)h << 16);
}
// truncation hi/lo split: x ~= hi + lo, |err| ~ 2^-16 |x|
__device__ inline void tsplit(float x, unsigned short& hi, unsigned short& lo) {
    unsigned u = __builtin_bit_cast(unsigned, x);
    hi = (unsigned short)(u >> 16);
    float r = x - __builtin_bit_cast(float, u & 0xffff0000u);
    lo = (unsigned short)(__builtin_bit_cast(unsigned, r) >> 16);
}
// head1 LDS slot swizzle (R21): bijective in-fragment permutation.
__device__ inline int fo(int r, int k) {
    return (((r + 2 * k) & 15) + 16 * k) * 8;
}

// ---------------------------------------------------------------------------
// Merged prep: blockIdx-partitioned (R19-verified).
//   bid 0            : build T1/T2 + emit A-frag-order hi/lo Tf  (1 block)
//   bid 1..1920      : conv weights -> B-frag order WTall        (480 x 4)
//   bid 1921..9616   : Wh1 -> Wh1T bf16 transpose                (481 x 16)
//   bid 9617..11152  : H1/H2 bias broadcast                      (1536)
// ---------------------------------------------------------------------------
#define PREP_GRID 11153
__global__ __launch_bounds__(256) void prep_kernel(
    const int* __restrict__ ei, int E, int epg, unsigned short* __restrict__ Tf,
    const float* __restrict__ W1, const float* __restrict__ W2,
    const float* __restrict__ W3, const float* __restrict__ W4,
    unsigned short* __restrict__ WTall,
    const float* __restrict__ Wh1, unsigned short* __restrict__ Wh1T,
    float* __restrict__ H1, const float* __restrict__ bh1,
    float* __restrict__ H2, const float* __restrict__ bh2)
{
    __shared__ __align__(16) char ps[48640];
    const int bid = blockIdx.x;
    const int t   = threadIdx.x;

    if (bid == 0) {
        float* Ls   = (float*)ps;                 // 15376 B
        float* Ts   = (float*)(ps + 15376);       // 32768 B  ([2][4096] flat)
        int*   deg  = (int*)(ps + 48144);         // 248 B
        float* dinv = (float*)(ps + 48392);       // 248 B
        for (int i = t; i < NODES * NODES; i += 256) Ls[i] = 0.f;
        if (t < NODES) deg[t] = 0;
        __syncthreads();
        const int* row = ei;
        const int* col = ei + E;
        for (int j = t; j < epg; j += 256) atomicAdd(&deg[row[j]], 1);
        __syncthreads();
        if (t < NODES) dinv[t] = (deg[t] > 0) ? rsqrtf((float)deg[t]) : 0.f;
        __syncthreads();
        for (int j = t; j < epg; j += 256) {
            int r = row[j], c = col[j];
            atomicAdd(&Ls[r * NODES + c], -dinv[r] * dinv[c]);
        }
        __syncthreads();
        for (int idx = t; idx < 4096; idx += 256) {
            int r = idx >> 6, c = idx & 63;
            float t1 = 0.f, t2 = 0.f;
            if (r < NODES && c < NODES) {
                t1 = Ls[r * NODES + c];
                float s = 0.f;
                for (int j = 0; j < NODES; ++j) s += Ls[r * NODES + j] * Ls[j * NODES + c];
                t2 = 2.f * s - (r == c ? 1.f : 0.f);
            }
            Ts[idx]        = t1;
            Ts[4096 + idx] = t2;
        }
        __syncthreads();
        for (int idx = t; idx < 16384; idx += 256) {
            int j    = idx & 7;
            int lane = (idx >> 3) & 63;
            int pl   = (idx >> 9) & 1;
            int ks   = (idx >> 10) & 3;
            int w    = (idx >> 12) & 3;
            int m = (w & 1) * 32 + (lane & 31);
            int k = ks * 16 + (lane >> 5) * 8 + j;
            float v = Ts[(w >> 1) * 4096 + m * 64 + k];
            unsigned short hi, lo;
            tsplit(v, hi, lo);
            Tf[idx] = pl ? lo : hi;
        }
    } else if (bid < 1921) {
        const int li    = bid - 1;
        const int layer = li / 480;
        const int bx    = li - layer * 480;
        const float* W = (layer == 0) ? W1 : (layer == 1) ? W2 : (layer == 2) ? W3 : W4;
        const int d    = (layer == 0) ? 128 : (layer == 1) ? 190 : (layer == 2) ? 252 : 314;
        const int dpad = (layer == 0) ? 128 : (layer == 1) ? 192 : (layer == 2) ? 256 : 320;
        const int cum  = (layer == 0) ? 0 : (layer == 1) ? 4 : (layer == 2) ? 10 : 18;
        unsigned short* WTf = WTall + (size_t)cum * 12288;
        const int total = (dpad >> 5) * 12288;
        int idx = bx * 256 + t;
        if (idx >= total) return;
        int j    = idx & 7;
        int lane = (idx >> 3) & 63;
        int f    = idx >> 9;
        int nt   = f & 1;
        int pl   = (f >> 1) & 1;
        int ks   = (f >> 2) & 1;
        int seg  = (f >> 3) % 3;
        int ch   = (f >> 3) / 3;
        int n  = nt * 32 + (lane & 31);
        int kk = ch * 32 + ks * 16 + (lane >> 5) * 8 + j;
        float v = (n < NODES && kk < d) ? W[((size_t)seg * d + kk) * OUT_DIM + n] : 0.f;
        unsigned short hi, lo;
        tsplit(v, hi, lo);
        WTf[idx] = pl ? lo : hi;
    } else if (bid < 9617) {
        const int ti = bid - 1921;
        const int k0 = (ti % 481) * 32;
        const int n0 = (ti / 481) * 32;
        float (*T)[33] = (float(*)[33])ps;        // 4224 B
        {
            int kl = t >> 3, n4 = (t & 7) * 4;
            if (k0 + kl < FEAT) {
                float4 v = *(const float4*)&Wh1[(size_t)(k0 + kl) * LIN1 + n0 + n4];
                T[kl][n4] = v.x; T[kl][n4 + 1] = v.y; T[kl][n4 + 2] = v.z; T[kl][n4 + 3] = v.w;
            }
        }
        __syncthreads();
        {
            int nl = t >> 3, k4 = (t & 7) * 4;
            if (k0 + k4 + 3 < FEAT) {
                ushort4 o;
                o.x = f2bf(T[k4 + 0][nl]);
                o.y = f2bf(T[k4 + 1][nl]);
                o.z = f2bf(T[k4 + 2][nl]);
                o.w = f2bf(T[k4 + 3][nl]);
                *(ushort4*)&Wh1T[(size_t)(n0 + nl) * FEAT + k0 + k4] = o;
            }
        }
    } else {
        const int i = (bid - 9617) * 256 + t;
        const int n1 = BATCH * LIN1 / 4;          // 262144
        if (i < n1) {
            ((float4*)H1)[i] = ((const float4*)bh1)[i & (LIN1 / 4 - 1)];
        } else {
            int j = i - n1;                       // < BATCH*LIN2/4
            ((float4*)H2)[j] = ((const float4*)bh2)[j & (LIN2 / 4 - 1)];
        }
    }
}

// ---------------------------------------------------------------------------
// Fused 4-layer Cheb (R22): the R19 per-layer body verbatim, wrapped in a
// layer loop. Inter-layer: X248 write -> __syncthreads (vmcnt drain, same-CU
// L1/L2 visibility; R17-verified) -> next layer's staging reads.
// ---------------------------------------------------------------------------
__global__ __launch_bounds__(256, 4) void cheb_fused4(
    const float* __restrict__ x, float* __restrict__ X248,
    const unsigned short* __restrict__ WTall, const unsigned short* __restrict__ Tf,
    const float* __restrict__ b1, const float* __restrict__ b2,
    const float* __restrict__ b3, const float* __restrict__ b4)
{
    __shared__ __align__(16) unsigned short smem[17408];   // 34816 B union
    __shared__ float bias_s[256];

    unsigned short* hA = smem;            // [pl 2][row 64][40] hi/lo planes of h chunk
    unsigned short* Bs = smem + 5120;     // 24 frags x 512 (W chunk, frag order)

    const int tid  = threadIdx.x;
    const int g    = blockIdx.x;
    const int lane = tid & 63;
    const int wv   = tid >> 6;
    const int mtw  = wv >> 1, ntw = wv & 1;

    {   // preload all 4 biases
        const int ll = tid >> 6, c = tid & 63;
        const float* bp = (ll == 0) ? b1 : (ll == 1) ? b2 : (ll == 2) ? b3 : b4;
        bias_s[tid] = (c < OUT_DIM) ? bp[c] : 0.f;
    }
    __syncthreads();

    const int srow = tid >> 2;
    const int scg  = (tid & 3) * 8;

    #pragma unroll
    for (int l = 0; l < 4; ++l) {
        const int d      = (l == 0) ? 128 : (l == 1) ? 190 : (l == 2) ? 252 : 314;
        const int nchunk = (l == 0) ? 4   : (l == 1) ? 6   : (l == 2) ? 8   : 10;
        const unsigned short* WTf =
            WTall + (size_t)((l == 0) ? 0 : (l == 1) ? 4 : (l == 2) ? 10 : 18) * 12288;

        f32x16 acc[3];
        #pragma unroll
        for (int s = 0; s < 3; ++s)
            #pragma unroll
            for (int i = 0; i < 16; ++i) acc[s][i] = 0.f;

        float  vh[8];
        short8 breg[6];

#define LOADCH(cn)                                                             \
    do {                                                                       \
        const int gf_ = (cn) * 32 + scg;                                       \
        if (srow < NODES) {                                                    \
            if ((cn) * 32 < IN_DIM) {                                          \
                const float4* p_ = (const float4*)&x[(size_t)(g * NODES + srow) * IN_DIM + gf_]; \
                float4 a_ = p_[0], b_ = p_[1];                                 \
                vh[0] = a_.x; vh[1] = a_.y; vh[2] = a_.z; vh[3] = a_.w;        \
                vh[4] = b_.x; vh[5] = b_.y; vh[6] = b_.z; vh[7] = b_.w;        \
            } else if (gf_ + 8 <= d) {                                         \
                const float4* p_ = (const float4*)&X248[(size_t)(g * NODES + srow) * ACOLS + (gf_ - IN_DIM)]; \
                float4 a_ = p_[0], b_ = p_[1];                                 \
                vh[0] = a_.x; vh[1] = a_.y; vh[2] = a_.z; vh[3] = a_.w;        \
                vh[4] = b_.x; vh[5] = b_.y; vh[6] = b_.z; vh[7] = b_.w;        \
            } else {                                                           \
                _Pragma("unroll")                                              \
                for (int p = 0; p < 8; ++p)                                    \
                    vh[p] = (gf_ + p < d)                                      \
                        ? X248[(size_t)(g * NODES + srow) * ACOLS + (gf_ - IN_DIM) + p] : 0.f; \
            }                                                                  \
        } else {                                                               \
            _Pragma("unroll")                                                  \
            for (int p = 0; p < 8; ++p) vh[p] = 0.f;                           \
        }                                                                      \
        const short8* wsrc_ = (const short8*)(WTf + (size_t)(cn) * 12288);     \
        _Pragma("unroll")                                                      \
        for (int i = 0; i < 6; ++i) breg[i] = wsrc_[i * 256 + tid];            \
    } while (0)

        LOADCH(0);   // prologue

        for (int ch = 0; ch < nchunk; ++ch) {
            {
                short8 hi8, lo8;
                #pragma unroll
                for (int p = 0; p < 8; ++p) {
                    unsigned short h_, l_;
                    tsplit(vh[p], h_, l_);
                    hi8[p] = (short)h_; lo8[p] = (short)l_;
                }
                *(short8*)&hA[srow * 40 + scg]        = hi8;
                *(short8*)&hA[2560 + srow * 40 + scg] = lo8;
                #pragma unroll
                for (int i = 0; i < 6; ++i) ((short8*)Bs)[i * 256 + tid] = breg[i];
            }
            __syncthreads();   // A: staging visible
            if (ch + 1 < nchunk) LOADCH(ch + 1);   // issue next-chunk loads
            {
                const int arow = mtw * 32 + (lane & 31);
                const int akf  = (lane >> 5) * 8;
                #pragma unroll
                for (int ks = 0; ks < 2; ++ks) {
                    short8 ahi = *(const short8*)&hA[arow * 40 + ks * 16 + akf];
                    short8 alo = *(const short8*)&hA[2560 + arow * 40 + ks * 16 + akf];
                    #pragma unroll
                    for (int seg = 0; seg < 3; ++seg) {
                        const unsigned short* bp =
                            Bs + ((((seg * 2 + ks) * 2 + 0) * 2 + ntw) << 9) + lane * 8;
                        short8 bhi = *(const short8*)bp;
                        short8 blo = *(const short8*)(bp + 1024);   // +1 plane = +2 frags
                        acc[seg] = __builtin_amdgcn_mfma_f32_32x32x16_bf16(ahi, bhi, acc[seg], 0, 0, 0);
                        acc[seg] = __builtin_amdgcn_mfma_f32_32x32x16_bf16(ahi, blo, acc[seg], 0, 0, 0);
                        acc[seg] = __builtin_amdgcn_mfma_f32_32x32x16_bf16(alo, bhi, acc[seg], 0, 0, 0);
                    }
                }
            }
            __syncthreads();   // B: protects hA/Bs overwrite (and epilogue reuse)
        }
#undef LOADCH

        // ---- epilogue: out = S0 + T1@S1 + T2@S2
        short8 Tr[2][4][2];
        #pragma unroll
        for (int mat = 0; mat < 2; ++mat) {
            const int w = mat * 2 + mtw;
            #pragma unroll
            for (int ks = 0; ks < 4; ++ks)
                #pragma unroll
                for (int pl = 0; pl < 2; ++pl)
                    Tr[mat][ks][pl] =
                        *(const short8*)(Tf + (((size_t)(w * 4 + ks) * 2 + pl) << 9) + lane * 8);
        }
        {
            const int jb = (lane >> 5) * 4;     // j base within octet
            const int lq = lane & 31;
            #pragma unroll
            for (int q = 0; q < 4; ++q) {
                const int ks2 = mtw * 2 + (q >> 1);
                const int lp  = lq + 32 * (q & 1);
                us4 s1h, s1l, s2h, s2l;
                #pragma unroll
                for (int r = 0; r < 4; ++r) {
                    unsigned short hi_, lo_;
                    tsplit(acc[1][q * 4 + r], hi_, lo_);
                    s1h[r] = hi_; s1l[r] = lo_;
                    tsplit(acc[2][q * 4 + r], hi_, lo_);
                    s2h[r] = hi_; s2l[r] = lo_;
                }
                const int base = lp * 8 + jb;
                *(us4*)&smem[((((0 + ks2) * 2 + 0) * 2 + ntw) << 9) + base] = s1h;
                *(us4*)&smem[((((0 + ks2) * 2 + 1) * 2 + ntw) << 9) + base] = s1l;
                *(us4*)&smem[((((4 + ks2) * 2 + 0) * 2 + ntw) << 9) + base] = s2h;
                *(us4*)&smem[((((4 + ks2) * 2 + 1) * 2 + ntw) << 9) + base] = s2l;
            }
        }
        __syncthreads();
        f32x16 outv = acc[0];
        #pragma unroll
        for (int mat = 0; mat < 2; ++mat)
            #pragma unroll
            for (int ks = 0; ks < 4; ++ks) {
                const unsigned short* sp =
                    smem + ((((mat * 4 + ks) * 2 + 0) * 2 + ntw) << 9) + lane * 8;
                short8 shi = *(const short8*)sp;
                short8 slo = *(const short8*)(sp + 1024);
                outv = __builtin_amdgcn_mfma_f32_32x32x16_bf16(Tr[mat][ks][0], shi, outv, 0, 0, 0);
                outv = __builtin_amdgcn_mfma_f32_32x32x16_bf16(Tr[mat][ks][0], slo, outv, 0, 0, 0);
                outv = __builtin_amdgcn_mfma_f32_32x32x16_bf16(Tr[mat][ks][1], shi, outv, 0, 0, 0);
            }
        {
            const int c = ntw * 32 + (lane & 31);
            if (c < OUT_DIM) {
                const float bv = bias_s[l * 64 + c];
                const int mbase = mtw * 32 + 4 * (lane >> 5);
                #pragma unroll
                for (int reg = 0; reg < 16; ++reg) {
                    int m = mbase + (reg & 3) + 8 * (reg >> 2);
                    if (m < NODES) {
                        float v = fmaxf(outv[reg] + bv, 0.f);
                        X248[(size_t)(g * NODES + m) * ACOLS + 62 * l + c] = v;
                    }
                }
            }
        }
        __syncthreads();   // X writes drained/visible; smem free for next layer
    }
}

// ---------------------------------------------------------------------------
// Head GEMM1 (R21, measured 112.6us == best): R10 structure, split-K=8,
// fragment-order LDS with bijective slot swizzle. 12KB LDS.
// ---------------------------------------------------------------------------
#define SPLIT1 8
__global__ __launch_bounds__(256) void gemm_head1_mfma(
    const float* __restrict__ F32, const unsigned short* __restrict__ WT1,
    float* __restrict__ H1)
{
    __shared__ __align__(16) unsigned short A16[4 * 512];   //  4 KB, frag order
    __shared__ __align__(16) unsigned short B16[8 * 512];   //  8 KB, frag order
    const int tid  = threadIdx.x;
    const int lane = tid & 63;
    const int wv   = tid >> 6;
    const int bm = blockIdx.x, bnb = blockIdx.y, s = blockIdx.z;
    const int c0 = (481 * s) / SPLIT1, c1 = (481 * (s + 1)) / SPLIT1;
    const int mr = tid >> 2, kg = (tid & 3) * 8;      // A stage map
    const int mrB = tid >> 1, kgB = (tid & 1) * 16;   // B stage map
    const int aoff  = (mr >> 4) * 512 + fo(mr & 15, tid & 3);
    const int boff0 = (mrB >> 4) * 512 + fo(mrB & 15, (tid & 1) * 2);
    const int boff1 = (mrB >> 4) * 512 + fo(mrB & 15, (tid & 1) * 2 + 1);
    const int roff  = fo(lane & 15, lane >> 4);       // read slot (A and B)

    f32x4 acc[8];
    #pragma unroll
    for (int i = 0; i < 8; ++i) acc[i] = (f32x4){0.f, 0.f, 0.f, 0.f};

    float4 u0, u1;
    short8 bv0, bv1;
#define LOAD1(cn)                                                              \
    do {                                                                       \
        const int k_ = (cn) * 32 + kg;                                         \
        u0 = (float4){0.f, 0.f, 0.f, 0.f};                                     \
        u1 = (float4){0.f, 0.f, 0.f, 0.f};                                     \
        bv0 = (short8){0, 0, 0, 0, 0, 0, 0, 0};                                \
        bv1 = (short8){0, 0, 0, 0, 0, 0, 0, 0};                                \
        if (k_ + 8 <= FEAT) {                                                  \
            const float4* p_ = (const float4*)&F32[(size_t)(bm * 64 + mr) * FEAT + k_]; \
            u0 = p_[0]; u1 = p_[1];                                            \
        }                                                                      \
        const int kB_ = (cn) * 32 + kgB;                                       \
        if (kB_ + 8 <= FEAT)                                                   \
            bv0 = *(const short8*)&WT1[(size_t)(bnb * 128 + mrB) * FEAT + kB_]; \
        if (kB_ + 16 <= FEAT)                                                  \
            bv1 = *(const short8*)&WT1[(size_t)(bnb * 128 + mrB) * FEAT + kB_ + 8]; \
    } while (0)

    LOAD1(c0);   // prologue
    for (int ch = c0; ch < c1; ++ch) {
        {
            short8 av;
            av[0] = (short)f2bf(u0.x); av[1] = (short)f2bf(u0.y);
            av[2] = (short)f2bf(u0.z); av[3] = (short)f2bf(u0.w);
            av[4] = (short)f2bf(u1.x); av[5] = (short)f2bf(u1.y);
            av[6] = (short)f2bf(u1.z); av[7] = (short)f2bf(u1.w);
            *(short8*)&A16[aoff]  = av;
            *(short8*)&B16[boff0] = bv0;
            *(short8*)&B16[boff1] = bv1;
        }
        __syncthreads();
        if (ch + 1 < c1) LOAD1(ch + 1);
        short8 af = *(short8*)&A16[wv * 512 + roff];
        #pragma unroll
        for (int nt = 0; nt < 8; ++nt) {
            short8 bf = *(short8*)&B16[nt * 512 + roff];
            acc[nt] = __builtin_amdgcn_mfma_f32_16x16x32_bf16(af, bf, acc[nt], 0, 0, 0);
        }
        __syncthreads();
    }
#undef LOAD1
    const int m0 = bm * 64 + wv * 16 + (lane >> 4) * 4;
    #pragma unroll
    for (int nt = 0; nt < 8; ++nt) {
        int c = bnb * 128 + nt * 16 + (lane & 15);
        #pragma unroll
        for (int rg = 0; rg < 4; ++rg)
            atomicAdd(&H1[(size_t)(m0 + rg) * LIN1 + c], acc[nt][rg]);
    }
}

// ---------------------------------------------------------------------------
// GEMM2 fp32 (split-K=4): H2 += H1[2048,512] @ Wh2.
// ---------------------------------------------------------------------------
#define ACC16(av, bv) do {                              \
    acc[0][0] = fmaf((av).x, (bv).x, acc[0][0]);        \
    acc[0][1] = fmaf((av).x, (bv).y, acc[0][1]);        \
    acc[0][2] = fmaf((av).x, (bv).z, acc[0][2]);        \
    acc[0][3] = fmaf((av).x, (bv).w, acc[0][3]);        \
    acc[1][0] = fmaf((av).y, (bv).x, acc[1][0]);        \
    acc[1][1] = fmaf((av).y, (bv).y, acc[1][1]);        \
    acc[1][2] = fmaf((av).y, (bv).z, acc[1][2]);        \
    acc[1][3] = fmaf((av).y, (bv).w, acc[1][3]);        \
    acc[2][0] = fmaf((av).z, (bv).x, acc[2][0]);        \
    acc[2][1] = fmaf((av).z, (bv).y, acc[2][1]);        \
    acc[2][2] = fmaf((av).z, (bv).z, acc[2][2]);        \
    acc[2][3] = fmaf((av).z, (bv).w, acc[2][3]);        \
    acc[3][0] = fmaf((av).w, (bv).x, acc[3][0]);        \
    acc[3][1] = fmaf((av).w, (bv).y, acc[3][1]);        \
    acc[3][2] = fmaf((av).w, (bv).z, acc[3][2]);        \
    acc[3][3] = fmaf((av).w, (bv).w, acc[3][3]);        \
} while (0)

#define SPLIT2 4
__global__ __launch_bounds__(256) void gemm2_kernel(
    const float* __restrict__ A, const float* __restrict__ B,
    float* __restrict__ C)
{
    __shared__ __align__(16) float As[16 * 72];
    __shared__ __align__(16) float Bs[16 * 64];
    const int bm = blockIdx.x, bnb = blockIdx.y, s = blockIdx.z;
    const int tid = threadIdx.x;
    const int ty4 = (tid >> 4) * 4;
    const int tx4 = (tid & 15) * 4;
    const int kbeg = s * (LIN1 / SPLIT2);
    const int kend = kbeg + LIN1 / SPLIT2;
    float acc[4][4] = {};
    for (int k0 = kbeg; k0 < kend; k0 += 16) {
        for (int i = tid; i < 1024; i += 256) {
            int m = i >> 4, kt = i & 15;
            As[kt * 72 + m] = A[(size_t)(bm * 64 + m) * LIN1 + k0 + kt];
        }
        for (int i = tid; i < 1024; i += 256) {
            int kt = i >> 6, c = i & 63;
            Bs[kt * 64 + c] = B[(size_t)(k0 + kt) * LIN2 + bnb * 64 + c];
        }
        __syncthreads();
        #pragma unroll
        for (int kt = 0; kt < 16; ++kt) {
            const float4 av = *(const float4*)&As[kt * 72 + ty4];
            const float4 bv = *(const float4*)&Bs[kt * 64 + tx4];
            ACC16(av, bv);
        }
        __syncthreads();
    }
    const int b = bm * 64 + ty4, c = bnb * 64 + tx4;
    #pragma unroll
    for (int i = 0; i < 4; ++i)
        #pragma unroll
        for (int j = 0; j < 4; ++j)
            atomicAdd(&C[(size_t)(b + i) * LIN2 + c + j], acc[i][j]);
}

// ---------------------------------------------------------------------------
// BatchNorm (training stats, biased var) + ReLU, in place.
// ---------------------------------------------------------------------------
__global__ __launch_bounds__(256) void bn_relu_kernel(
    float* __restrict__ H, int C,
    const float* __restrict__ gamma, const float* __restrict__ beta)
{
    const int c  = blockIdx.x * 16 + (threadIdx.x & 15);
    const int rt = threadIdx.x >> 4;
    const int ct = threadIdx.x & 15;
    float s = 0.f, s2 = 0.f;
    for (int r = rt; r < BATCH; r += 16) {
        float v = H[(size_t)r * C + c];
        s += v; s2 += v * v;
    }
    __shared__ float Ss[16][16], S2s[16][16], sc_s[16], sh_s[16];
    Ss[rt][ct] = s; S2s[rt][ct] = s2;
    __syncthreads();
    if (rt == 0) {
        float ts = 0.f, ts2 = 0.f;
        #pragma unroll
        for (int i = 0; i < 16; ++i) { ts += Ss[i][ct]; ts2 += S2s[i][ct]; }
        float m   = ts * (1.f / BATCH);
        float var = ts2 * (1.f / BATCH) - m * m;
        float sc  = gamma[c] * rsqrtf(var + BN_EPS);
        sc_s[ct] = sc;
        sh_s[ct] = beta[c] - m * sc;
    }
    __syncthreads();
    const float sc = sc_s[ct], sh = sh_s[ct];
    for (int r = rt; r < BATCH; r += 16) {
        float v = H[(size_t)r * C + c];
        H[(size_t)r * C + c] = fmaxf(fmaf(v, sc, sh), 0.f);
    }
}

// ---------------------------------------------------------------------------
// Final: logits = H2 @ Wh3 + bh3, softmax over 3 classes.
// ---------------------------------------------------------------------------
__global__ __launch_bounds__(256) void final_kernel(
    const float* __restrict__ H2, const float* __restrict__ Wh3,
    const float* __restrict__ bh3, float* __restrict__ out)
{
    __shared__ float Ws[LIN2 * NCLS];
    __shared__ float bs[NCLS];
    const int tid = threadIdx.x;
    for (int i = tid; i < LIN2 * NCLS; i += 256) Ws[i] = Wh3[i];
    if (tid < NCLS) bs[tid] = bh3[tid];
    __syncthreads();
    const int r = blockIdx.x * 256 + tid;
    float a0 = bs[0], a1 = bs[1], a2 = bs[2];
    const float4* row = (const float4*)&H2[(size_t)r * LIN2];
    for (int k4 = 0; k4 < LIN2 / 4; ++k4) {
        float4 h = row[k4];
        int k = k4 * 4;
        a0 = fmaf(h.x, Ws[(k + 0) * 3 + 0], a0);
        a1 = fmaf(h.x, Ws[(k + 0) * 3 + 1], a1);
        a2 = fmaf(h.x, Ws[(k + 0) * 3 + 2], a2);
        a0 = fmaf(h.y, Ws[(k + 1) * 3 + 0], a0);
        a1 = fmaf(h.y, Ws[(k + 1) * 3 + 1], a1);
        a2 = fmaf(h.y, Ws[(k + 1) * 3 + 2], a2);
        a0 = fmaf(h.z, Ws[(k + 2) * 3 + 0], a0);
        a1 = fmaf(h.z, Ws[(k + 2) * 3 + 1], a1);
        a2 = fmaf(h.z, Ws[(k + 2) * 3 + 2], a2);
        a0 = fmaf(h.w, Ws[(k + 3) * 3 + 0], a0);
        a1 = fmaf(h.w, Ws[(k + 3) * 3 + 1], a1);
        a2 = fmaf(h.w, Ws[(k + 3) * 3 + 2], a2);
    }
    float mx = fmaxf(a0, fmaxf(a1, a2));
    float e0 = expf(a0 - mx), e1 = expf(a1 - mx), e2 = expf(a2 - mx);
    float inv = 1.f / (e0 + e1 + e2);
    out[r * 3 + 0] = e0 * inv;
    out[r * 3 + 1] = e1 * inv;
    out[r * 3 + 2] = e2 * inv;
}

// ---------------------------------------------------------------------------
extern "C" void kernel_launch(void* const* d_in, const int* in_sizes, int n_in,
                              void* d_out, int out_size, void* d_ws, size_t ws_size,
                              hipStream_t stream)
{
    const float* x   = (const float*)d_in[0];
    const int*   ei  = (const int*)  d_in[1];
    const float* W1  = (const float*)d_in[2];
    const float* b1  = (const float*)d_in[3];
    const float* W2  = (const float*)d_in[4];
    const float* b2  = (const float*)d_in[5];
    const float* W3  = (const float*)d_in[6];
    const float* b3  = (const float*)d_in[7];
    const float* W4  = (const float*)d_in[8];
    const float* b4  = (const float*)d_in[9];
    const float* Wh1 = (const float*)d_in[10];
    const float* bh1 = (const float*)d_in[11];
    const float* g1  = (const float*)d_in[12];
    const float* be1 = (const float*)d_in[13];
    const float* Wh2 = (const float*)d_in[14];
    const float* bh2 = (const float*)d_in[15];
    const float* g2  = (const float*)d_in[16];
    const float* be2 = (const float*)d_in[17];
    const float* Wh3 = (const float*)d_in[18];
    const float* bh3 = (const float*)d_in[19];
    float* out = (float*)d_out;

    // workspace layout -- TOTAL ~148.7 MB (R10/R14-proven offsets)
    char* ws = (char*)d_ws;
    unsigned short* Tf    = (unsigned short*)(ws + 32768);           // 32768
    unsigned short* WTall = (unsigned short*)(ws + 65536);           // 688128
    unsigned short* Wh1T  = (unsigned short*)(ws + 753664);          // 15,745,024
    float* X248 = (float*)(ws + 16498688);                           // 125,960,192
    float* H1   = (float*)(ws + 142458880);                          // 4,194,304
    float* H2   = (float*)(ws + 146653184);                          // 2,097,152

    const int E   = in_sizes[1] / 2;   // 1,015,808
    const int epg = E / BATCH;         // 496 edges of graph 0

    prep_kernel<<<PREP_GRID, 256, 0, stream>>>(
        ei, E, epg, Tf, W1, W2, W3, W4, WTall, Wh1, Wh1T, H1, bh1, H2, bh2);

    cheb_fused4<<<BATCH, 256, 0, stream>>>(x, X248, WTall, Tf, b1, b2, b3, b4);

    gemm_head1_mfma<<<dim3(32, 4, SPLIT1), 256, 0, stream>>>(X248, Wh1T, H1);
    bn_relu_kernel<<<LIN1 / 16, 256, 0, stream>>>(H1, LIN1, g1, be1);

    gemm2_kernel<<<dim3(32, 4, SPLIT2), 256, 0, stream>>>(H1, Wh2, H2);
    bn_relu_kernel<<<LIN2 / 16, 256, 0, stream>>>(H2, LIN2, g2, be2);

    final_kernel<<<BATCH / 256, 256, 0, stream>>>(H2, Wh3, bh3, out);
}

// Round 11
// 518.815 us; speedup vs baseline: 1.2471x; 1.2471x over previous
//
#include <hip/hip_runtime.h>

// ---------------------------------------------------------------------------
// JointlyTrainModel round 24: R23 with the final_kernel GRID FIX.
// R23 post-mortem: absmax 0.875 was a launch-config bug -- final_kernel was
// launched with 8 blocks (BATCH/32/8) but each block covers 32 rows -> rows
// 256..2047 never written. Fix: BATCH/32 = 64 blocks. Everything else
// byte-identical to R23 (BN split into wide stats + fused apply; final
// 8 lanes/row + shfl reduce; R19 cheb; R21 head1).
// ---------------------------------------------------------------------------

#define NODES   62
#define BATCH   2048
#define NTOT    (NODES * BATCH)     // 126976
#define IN_DIM  128
#define OUT_DIM 62
#define ACOLS   248                 // 4*62 activation cols
#define FEAT    15376               // 62*248
#define LIN1    512
#define LIN2    256
#define NCLS    3
#define BN_EPS  1e-5f

typedef __attribute__((ext_vector_type(8)))  short  short8;
typedef __attribute__((ext_vector_type(4)))  float  f32x4;
typedef __attribute__((ext_vector_type(16))) float  f32x16;
typedef __attribute__((ext_vector_type(4)))  unsigned short us4;

__device__ inline unsigned short f2bf(float x) {   // RTNE
    unsigned u = __builtin_bit_cast(unsigned, x);
    return (unsigned short)((u + 0x7fffu + ((u >> 16) & 1u)) >> 16);
}
__device__ inline float bf2f(unsigned short h) {
    return __builtin_bit_cast(float, (unsigned)h << 16);
}
// truncation hi/lo split: x ~= hi + lo, |err| ~ 2^-16 |x|
__device__ inline void tsplit(float x, unsigned short& hi, unsigned short& lo) {
    unsigned u = __builtin_bit_cast(unsigned, x);
    hi = (unsigned short)(u >> 16);
    float r = x - __builtin_bit_cast(float, u & 0xffff0000u);
    lo = (unsigned short)(__builtin_bit_cast(unsigned, r) >> 16);
}
// head1 LDS slot swizzle (R21): bijective in-fragment permutation.
__device__ inline int fo(int r, int k) {
    return (((r + 2 * k) & 15) + 16 * k) * 8;
}

// ---------------------------------------------------------------------------
// Merged prep: blockIdx-partitioned (R19-verified) + stats-scratch zeroing.
//   bid 0            : build T1/T2 + emit A-frag-order hi/lo Tf  (1 block)
//   bid 1..1920      : conv weights -> B-frag order WTall        (480 x 4)
//   bid 1921..9616   : Wh1 -> Wh1T bf16 transpose                (481 x 16)
//   bid 9617..11154  : H1/H2 bias broadcast + BN-stats zeroing   (1538)
// ---------------------------------------------------------------------------
#define PREP_GRID 11155
__global__ __launch_bounds__(256) void prep_kernel(
    const int* __restrict__ ei, int E, int epg, unsigned short* __restrict__ Tf,
    const float* __restrict__ W1, const float* __restrict__ W2,
    const float* __restrict__ W3, const float* __restrict__ W4,
    unsigned short* __restrict__ WTall,
    const float* __restrict__ Wh1, unsigned short* __restrict__ Wh1T,
    float* __restrict__ H1, const float* __restrict__ bh1,
    float* __restrict__ H2, const float* __restrict__ bh2,
    float* __restrict__ stats)
{
    __shared__ __align__(16) char ps[48640];
    const int bid = blockIdx.x;
    const int t   = threadIdx.x;

    if (bid == 0) {
        float* Ls   = (float*)ps;                 // 15376 B
        float* Ts   = (float*)(ps + 15376);       // 32768 B  ([2][4096] flat)
        int*   deg  = (int*)(ps + 48144);         // 248 B
        float* dinv = (float*)(ps + 48392);       // 248 B
        for (int i = t; i < NODES * NODES; i += 256) Ls[i] = 0.f;
        if (t < NODES) deg[t] = 0;
        __syncthreads();
        const int* row = ei;
        const int* col = ei + E;
        for (int j = t; j < epg; j += 256) atomicAdd(&deg[row[j]], 1);
        __syncthreads();
        if (t < NODES) dinv[t] = (deg[t] > 0) ? rsqrtf((float)deg[t]) : 0.f;
        __syncthreads();
        for (int j = t; j < epg; j += 256) {
            int r = row[j], c = col[j];
            atomicAdd(&Ls[r * NODES + c], -dinv[r] * dinv[c]);
        }
        __syncthreads();
        for (int idx = t; idx < 4096; idx += 256) {
            int r = idx >> 6, c = idx & 63;
            float t1 = 0.f, t2 = 0.f;
            if (r < NODES && c < NODES) {
                t1 = Ls[r * NODES + c];
                float s = 0.f;
                for (int j = 0; j < NODES; ++j) s += Ls[r * NODES + j] * Ls[j * NODES + c];
                t2 = 2.f * s - (r == c ? 1.f : 0.f);
            }
            Ts[idx]        = t1;
            Ts[4096 + idx] = t2;
        }
        __syncthreads();
        for (int idx = t; idx < 16384; idx += 256) {
            int j    = idx & 7;
            int lane = (idx >> 3) & 63;
            int pl   = (idx >> 9) & 1;
            int ks   = (idx >> 10) & 3;
            int w    = (idx >> 12) & 3;
            int m = (w & 1) * 32 + (lane & 31);
            int k = ks * 16 + (lane >> 5) * 8 + j;
            float v = Ts[(w >> 1) * 4096 + m * 64 + k];
            unsigned short hi, lo;
            tsplit(v, hi, lo);
            Tf[idx] = pl ? lo : hi;
        }
    } else if (bid < 1921) {
        const int li    = bid - 1;
        const int layer = li / 480;
        const int bx    = li - layer * 480;
        const float* W = (layer == 0) ? W1 : (layer == 1) ? W2 : (layer == 2) ? W3 : W4;
        const int d    = (layer == 0) ? 128 : (layer == 1) ? 190 : (layer == 2) ? 252 : 314;
        const int dpad = (layer == 0) ? 128 : (layer == 1) ? 192 : (layer == 2) ? 256 : 320;
        const int cum  = (layer == 0) ? 0 : (layer == 1) ? 4 : (layer == 2) ? 10 : 18;
        unsigned short* WTf = WTall + (size_t)cum * 12288;
        const int total = (dpad >> 5) * 12288;
        int idx = bx * 256 + t;
        if (idx >= total) return;
        int j    = idx & 7;
        int lane = (idx >> 3) & 63;
        int f    = idx >> 9;
        int nt   = f & 1;
        int pl   = (f >> 1) & 1;
        int ks   = (f >> 2) & 1;
        int seg  = (f >> 3) % 3;
        int ch   = (f >> 3) / 3;
        int n  = nt * 32 + (lane & 31);
        int kk = ch * 32 + ks * 16 + (lane >> 5) * 8 + j;
        float v = (n < NODES && kk < d) ? W[((size_t)seg * d + kk) * OUT_DIM + n] : 0.f;
        unsigned short hi, lo;
        tsplit(v, hi, lo);
        WTf[idx] = pl ? lo : hi;
    } else if (bid < 9617) {
        const int ti = bid - 1921;
        const int k0 = (ti % 481) * 32;
        const int n0 = (ti / 481) * 32;
        float (*T)[33] = (float(*)[33])ps;        // 4224 B
        {
            int kl = t >> 3, n4 = (t & 7) * 4;
            if (k0 + kl < FEAT) {
                float4 v = *(const float4*)&Wh1[(size_t)(k0 + kl) * LIN1 + n0 + n4];
                T[kl][n4] = v.x; T[kl][n4 + 1] = v.y; T[kl][n4 + 2] = v.z; T[kl][n4 + 3] = v.w;
            }
        }
        __syncthreads();
        {
            int nl = t >> 3, k4 = (t & 7) * 4;
            if (k0 + k4 + 3 < FEAT) {
                ushort4 o;
                o.x = f2bf(T[k4 + 0][nl]);
                o.y = f2bf(T[k4 + 1][nl]);
                o.z = f2bf(T[k4 + 2][nl]);
                o.w = f2bf(T[k4 + 3][nl]);
                *(ushort4*)&Wh1T[(size_t)(n0 + nl) * FEAT + k0 + k4] = o;
            }
        }
    } else {
        const int i = (bid - 9617) * 256 + t;
        const int n1 = BATCH * LIN1 / 4;          // 262144
        const int n2 = BATCH * LIN2 / 4;          // 131072
        if (i < n1) {
            ((float4*)H1)[i] = ((const float4*)bh1)[i & (LIN1 / 4 - 1)];
        } else if (i - n1 < n2) {
            int j = i - n1;
            ((float4*)H2)[j] = ((const float4*)bh2)[j & (LIN2 / 4 - 1)];
        } else {
            int j = i - n1 - n2;                  // < 512
            if (j < 512)
                ((float4*)stats)[j] = (float4){0.f, 0.f, 0.f, 0.f};
        }
    }
}

// ---------------------------------------------------------------------------
// Fused Cheb layer (R19, measured best): S_k = h@W_k over chunks
// (2 barriers + 18 mfma per chunk), then out = S0 + T1@S1 + T2@S2.
// ---------------------------------------------------------------------------
__global__ __launch_bounds__(256, 4) void cheb_mfma(
    const float* __restrict__ x, float* __restrict__ X248,
    const unsigned short* __restrict__ WTf, const unsigned short* __restrict__ Tf,
    const float* __restrict__ bias, int d, int dpad)
{
    __shared__ __align__(16) unsigned short smem[17408];   // 34816 B union
    __shared__ float bias_s[64];

    unsigned short* hA = smem;            // [pl 2][row 64][40] hi/lo planes of h chunk
    unsigned short* Bs = smem + 5120;     // 24 frags x 512 (W chunk, frag order)

    const int tid  = threadIdx.x;
    const int g    = blockIdx.x;
    const int lane = tid & 63;
    const int wv   = tid >> 6;
    const int mtw  = wv >> 1, ntw = wv & 1;

    if (tid < 64) bias_s[tid] = (tid < OUT_DIM) ? bias[tid] : 0.f;

    const int srow = tid >> 2;
    const int scg  = (tid & 3) * 8;

    const int nchunk = dpad >> 5;

    f32x16 acc[3];
    #pragma unroll
    for (int s = 0; s < 3; ++s)
        #pragma unroll
        for (int i = 0; i < 16; ++i) acc[s][i] = 0.f;

    float  vh[8];
    short8 breg[6];

#define LOADCH(cn)                                                             \
    do {                                                                       \
        const int gf_ = (cn) * 32 + scg;                                       \
        if (srow < NODES) {                                                    \
            if ((cn) * 32 < IN_DIM) {                                          \
                const float4* p_ = (const float4*)&x[(size_t)(g * NODES + srow) * IN_DIM + gf_]; \
                float4 a_ = p_[0], b_ = p_[1];                                 \
                vh[0] = a_.x; vh[1] = a_.y; vh[2] = a_.z; vh[3] = a_.w;        \
                vh[4] = b_.x; vh[5] = b_.y; vh[6] = b_.z; vh[7] = b_.w;        \
            } else if (gf_ + 8 <= d) {                                         \
                const float4* p_ = (const float4*)&X248[(size_t)(g * NODES + srow) * ACOLS + (gf_ - IN_DIM)]; \
                float4 a_ = p_[0], b_ = p_[1];                                 \
                vh[0] = a_.x; vh[1] = a_.y; vh[2] = a_.z; vh[3] = a_.w;        \
                vh[4] = b_.x; vh[5] = b_.y; vh[6] = b_.z; vh[7] = b_.w;        \
            } else {                                                           \
                _Pragma("unroll")                                              \
                for (int p = 0; p < 8; ++p)                                    \
                    vh[p] = (gf_ + p < d)                                      \
                        ? X248[(size_t)(g * NODES + srow) * ACOLS + (gf_ - IN_DIM) + p] : 0.f; \
            }                                                                  \
        } else {                                                               \
            _Pragma("unroll")                                                  \
            for (int p = 0; p < 8; ++p) vh[p] = 0.f;                           \
        }                                                                      \
        const short8* wsrc_ = (const short8*)(WTf + (size_t)(cn) * 12288);     \
        _Pragma("unroll")                                                      \
        for (int i = 0; i < 6; ++i) breg[i] = wsrc_[i * 256 + tid];            \
    } while (0)

    LOADCH(0);   // prologue

    for (int ch = 0; ch < nchunk; ++ch) {
        {
            short8 hi8, lo8;
            #pragma unroll
            for (int p = 0; p < 8; ++p) {
                unsigned short h_, l_;
                tsplit(vh[p], h_, l_);
                hi8[p] = (short)h_; lo8[p] = (short)l_;
            }
            *(short8*)&hA[srow * 40 + scg]        = hi8;
            *(short8*)&hA[2560 + srow * 40 + scg] = lo8;
            #pragma unroll
            for (int i = 0; i < 6; ++i) ((short8*)Bs)[i * 256 + tid] = breg[i];
        }
        __syncthreads();   // A: staging visible
        if (ch + 1 < nchunk) LOADCH(ch + 1);   // issue next-chunk loads
        {
            const int arow = mtw * 32 + (lane & 31);
            const int akf  = (lane >> 5) * 8;
            #pragma unroll
            for (int ks = 0; ks < 2; ++ks) {
                short8 ahi = *(const short8*)&hA[arow * 40 + ks * 16 + akf];
                short8 alo = *(const short8*)&hA[2560 + arow * 40 + ks * 16 + akf];
                #pragma unroll
                for (int seg = 0; seg < 3; ++seg) {
                    const unsigned short* bp =
                        Bs + ((((seg * 2 + ks) * 2 + 0) * 2 + ntw) << 9) + lane * 8;
                    short8 bhi = *(const short8*)bp;
                    short8 blo = *(const short8*)(bp + 1024);   // +1 plane = +2 frags
                    acc[seg] = __builtin_amdgcn_mfma_f32_32x32x16_bf16(ahi, bhi, acc[seg], 0, 0, 0);
                    acc[seg] = __builtin_amdgcn_mfma_f32_32x32x16_bf16(ahi, blo, acc[seg], 0, 0, 0);
                    acc[seg] = __builtin_amdgcn_mfma_f32_32x32x16_bf16(alo, bhi, acc[seg], 0, 0, 0);
                }
            }
        }
        __syncthreads();   // B: protects hA/Bs overwrite (and epilogue reuse)
    }
#undef LOADCH

    // ---- epilogue: out = S0 + T1@S1 + T2@S2
    short8 Tr[2][4][2];
    #pragma unroll
    for (int mat = 0; mat < 2; ++mat) {
        const int w = mat * 2 + mtw;
        #pragma unroll
        for (int ks = 0; ks < 4; ++ks)
            #pragma unroll
            for (int pl = 0; pl < 2; ++pl)
                Tr[mat][ks][pl] =
                    *(const short8*)(Tf + (((size_t)(w * 4 + ks) * 2 + pl) << 9) + lane * 8);
    }
    {
        const int jb = (lane >> 5) * 4;     // j base within octet
        const int lq = lane & 31;
        #pragma unroll
        for (int q = 0; q < 4; ++q) {
            const int ks2 = mtw * 2 + (q >> 1);
            const int lp  = lq + 32 * (q & 1);
            us4 s1h, s1l, s2h, s2l;
            #pragma unroll
            for (int r = 0; r < 4; ++r) {
                unsigned short hi_, lo_;
                tsplit(acc[1][q * 4 + r], hi_, lo_);
                s1h[r] = hi_; s1l[r] = lo_;
                tsplit(acc[2][q * 4 + r], hi_, lo_);
                s2h[r] = hi_; s2l[r] = lo_;
            }
            const int base = lp * 8 + jb;
            *(us4*)&smem[((((0 + ks2) * 2 + 0) * 2 + ntw) << 9) + base] = s1h;
            *(us4*)&smem[((((0 + ks2) * 2 + 1) * 2 + ntw) << 9) + base] = s1l;
            *(us4*)&smem[((((4 + ks2) * 2 + 0) * 2 + ntw) << 9) + base] = s2h;
            *(us4*)&smem[((((4 + ks2) * 2 + 1) * 2 + ntw) << 9) + base] = s2l;
        }
    }
    __syncthreads();
    f32x16 out = acc[0];
    #pragma unroll
    for (int mat = 0; mat < 2; ++mat)
        #pragma unroll
        for (int ks = 0; ks < 4; ++ks) {
            const unsigned short* sp =
                smem + ((((mat * 4 + ks) * 2 + 0) * 2 + ntw) << 9) + lane * 8;
            short8 shi = *(const short8*)sp;
            short8 slo = *(const short8*)(sp + 1024);
            out = __builtin_amdgcn_mfma_f32_32x32x16_bf16(Tr[mat][ks][0], shi, out, 0, 0, 0);
            out = __builtin_amdgcn_mfma_f32_32x32x16_bf16(Tr[mat][ks][0], slo, out, 0, 0, 0);
            out = __builtin_amdgcn_mfma_f32_32x32x16_bf16(Tr[mat][ks][1], shi, out, 0, 0, 0);
        }
    {
        const int c = ntw * 32 + (lane & 31);
        if (c < OUT_DIM) {
            const int mbase = mtw * 32 + 4 * (lane >> 5);
            #pragma unroll
            for (int reg = 0; reg < 16; ++reg) {
                int m = mbase + (reg & 3) + 8 * (reg >> 2);
                if (m < NODES) {
                    float v = fmaxf(out[reg] + bias_s[c], 0.f);
                    X248[(size_t)(g * NODES + m) * ACOLS + (d - IN_DIM) + c] = v;
                }
            }
        }
    }
}

// ---------------------------------------------------------------------------
// Head GEMM1 (R21, measured 112.6us): R10 structure, split-K=8,
// fragment-order LDS with bijective slot swizzle. 12KB LDS.
// ---------------------------------------------------------------------------
#define SPLIT1 8
__global__ __launch_bounds__(256) void gemm_head1_mfma(
    const float* __restrict__ F32, const unsigned short* __restrict__ WT1,
    float* __restrict__ H1)
{
    __shared__ __align__(16) unsigned short A16[4 * 512];   //  4 KB, frag order
    __shared__ __align__(16) unsigned short B16[8 * 512];   //  8 KB, frag order
    const int tid  = threadIdx.x;
    const int lane = tid & 63;
    const int wv   = tid >> 6;
    const int bm = blockIdx.x, bnb = blockIdx.y, s = blockIdx.z;
    const int c0 = (481 * s) / SPLIT1, c1 = (481 * (s + 1)) / SPLIT1;
    const int mr = tid >> 2, kg = (tid & 3) * 8;      // A stage map
    const int mrB = tid >> 1, kgB = (tid & 1) * 16;   // B stage map
    const int aoff  = (mr >> 4) * 512 + fo(mr & 15, tid & 3);
    const int boff0 = (mrB >> 4) * 512 + fo(mrB & 15, (tid & 1) * 2);
    const int boff1 = (mrB >> 4) * 512 + fo(mrB & 15, (tid & 1) * 2 + 1);
    const int roff  = fo(lane & 15, lane >> 4);       // read slot (A and B)

    f32x4 acc[8];
    #pragma unroll
    for (int i = 0; i < 8; ++i) acc[i] = (f32x4){0.f, 0.f, 0.f, 0.f};

    float4 u0, u1;
    short8 bv0, bv1;
#define LOAD1(cn)                                                              \
    do {                                                                       \
        const int k_ = (cn) * 32 + kg;                                         \
        u0 = (float4){0.f, 0.f, 0.f, 0.f};                                     \
        u1 = (float4){0.f, 0.f, 0.f, 0.f};                                     \
        bv0 = (short8){0, 0, 0, 0, 0, 0, 0, 0};                                \
        bv1 = (short8){0, 0, 0, 0, 0, 0, 0, 0};                                \
        if (k_ + 8 <= FEAT) {                                                  \
            const float4* p_ = (const float4*)&F32[(size_t)(bm * 64 + mr) * FEAT + k_]; \
            u0 = p_[0]; u1 = p_[1];                                            \
        }                                                                      \
        const int kB_ = (cn) * 32 + kgB;                                       \
        if (kB_ + 8 <= FEAT)                                                   \
            bv0 = *(const short8*)&WT1[(size_t)(bnb * 128 + mrB) * FEAT + kB_]; \
        if (kB_ + 16 <= FEAT)                                                  \
            bv1 = *(const short8*)&WT1[(size_t)(bnb * 128 + mrB) * FEAT + kB_ + 8]; \
    } while (0)

    LOAD1(c0);   // prologue
    for (int ch = c0; ch < c1; ++ch) {
        {
            short8 av;
            av[0] = (short)f2bf(u0.x); av[1] = (short)f2bf(u0.y);
            av[2] = (short)f2bf(u0.z); av[3] = (short)f2bf(u0.w);
            av[4] = (short)f2bf(u1.x); av[5] = (short)f2bf(u1.y);
            av[6] = (short)f2bf(u1.z); av[7] = (short)f2bf(u1.w);
            *(short8*)&A16[aoff]  = av;
            *(short8*)&B16[boff0] = bv0;
            *(short8*)&B16[boff1] = bv1;
        }
        __syncthreads();
        if (ch + 1 < c1) LOAD1(ch + 1);
        short8 af = *(short8*)&A16[wv * 512 + roff];
        #pragma unroll
        for (int nt = 0; nt < 8; ++nt) {
            short8 bf = *(short8*)&B16[nt * 512 + roff];
            acc[nt] = __builtin_amdgcn_mfma_f32_16x16x32_bf16(af, bf, acc[nt], 0, 0, 0);
        }
        __syncthreads();
    }
#undef LOAD1
    const int m0 = bm * 64 + wv * 16 + (lane >> 4) * 4;
    #pragma unroll
    for (int nt = 0; nt < 8; ++nt) {
        int c = bnb * 128 + nt * 16 + (lane & 15);
        #pragma unroll
        for (int rg = 0; rg < 4; ++rg)
            atomicAdd(&H1[(size_t)(m0 + rg) * LIN1 + c], acc[nt][rg]);
    }
}

// ---------------------------------------------------------------------------
// BN stats (wide): grid (C/16, 16), 256 threads; 8 row-iters/thread;
// per-column partial sums -> fp32 atomicAdd into Sg/S2g (zeroed in prep).
// ---------------------------------------------------------------------------
__global__ __launch_bounds__(256) void bn_stats(
    const float* __restrict__ H, int C,
    float* __restrict__ Sg, float* __restrict__ S2g)
{
    const int ct = threadIdx.x & 15;
    const int rt = threadIdx.x >> 4;                 // 0..15
    const int c  = blockIdx.x * 16 + ct;
    const int r0 = blockIdx.y * 16 + rt;             // 256 row-threads over y
    float s = 0.f, s2 = 0.f;
    for (int r = r0; r < BATCH; r += 256) {
        float v = H[(size_t)r * C + c];
        s += v; s2 += v * v;
    }
    __shared__ float Ss[16][17], S2s[16][17];
    Ss[rt][ct] = s; S2s[rt][ct] = s2;
    __syncthreads();
    if (rt == 0) {
        float ts = 0.f, ts2 = 0.f;
        #pragma unroll
        for (int i = 0; i < 16; ++i) { ts += Ss[i][ct]; ts2 += S2s[i][ct]; }
        atomicAdd(&Sg[c], ts);
        atomicAdd(&S2g[c], ts2);
    }
}

// ---------------------------------------------------------------------------
// GEMM2 fp32 (split-K=4) with FUSED bn1 apply + relu on the A staging:
// H2 += relu(bn(H1)) @ Wh2.
// ---------------------------------------------------------------------------
#define ACC16(av, bv) do {                              \
    acc[0][0] = fmaf((av).x, (bv).x, acc[0][0]);        \
    acc[0][1] = fmaf((av).x, (bv).y, acc[0][1]);        \
    acc[0][2] = fmaf((av).x, (bv).z, acc[0][2]);        \
    acc[0][3] = fmaf((av).x, (bv).w, acc[0][3]);        \
    acc[1][0] = fmaf((av).y, (bv).x, acc[1][0]);        \
    acc[1][1] = fmaf((av).y, (bv).y, acc[1][1]);        \
    acc[1][2] = fmaf((av).y, (bv).z, acc[1][2]);        \
    acc[1][3] = fmaf((av).y, (bv).w, acc[1][3]);        \
    acc[2][0] = fmaf((av).z, (bv).x, acc[2][0]);        \
    acc[2][1] = fmaf((av).z, (bv).y, acc[2][1]);        \
    acc[2][2] = fmaf((av).z, (bv).z, acc[2][2]);        \
    acc[2][3] = fmaf((av).z, (bv).w, acc[2][3]);        \
    acc[3][0] = fmaf((av).w, (bv).x, acc[3][0]);        \
    acc[3][1] = fmaf((av).w, (bv).y, acc[3][1]);        \
    acc[3][2] = fmaf((av).w, (bv).z, acc[3][2]);        \
    acc[3][3] = fmaf((av).w, (bv).w, acc[3][3]);        \
} while (0)

#define SPLIT2 4
__global__ __launch_bounds__(256) void gemm2_kernel(
    const float* __restrict__ A, const float* __restrict__ B,
    float* __restrict__ C,
    const float* __restrict__ Sg1, const float* __restrict__ S2g1,
    const float* __restrict__ g1, const float* __restrict__ be1)
{
    __shared__ __align__(16) float As[16 * 72];
    __shared__ __align__(16) float Bs[16 * 64];
    __shared__ float scs[128], shs[128];
    const int bm = blockIdx.x, bnb = blockIdx.y, s = blockIdx.z;
    const int tid = threadIdx.x;
    const int ty4 = (tid >> 4) * 4;
    const int tx4 = (tid & 15) * 4;
    const int kbeg = s * (LIN1 / SPLIT2);
    const int kend = kbeg + LIN1 / SPLIT2;
    if (tid < 128) {
        const int k = kbeg + tid;
        float mn  = Sg1[k] * (1.f / BATCH);
        float var = S2g1[k] * (1.f / BATCH) - mn * mn;
        float sc  = g1[k] * rsqrtf(var + BN_EPS);
        scs[tid] = sc;
        shs[tid] = be1[k] - mn * sc;
    }
    __syncthreads();
    float acc[4][4] = {};
    for (int k0 = kbeg; k0 < kend; k0 += 16) {
        for (int i = tid; i < 1024; i += 256) {
            int m = i >> 4, kt = i & 15;
            float raw = A[(size_t)(bm * 64 + m) * LIN1 + k0 + kt];
            int kl = k0 + kt - kbeg;
            As[kt * 72 + m] = fmaxf(fmaf(raw, scs[kl], shs[kl]), 0.f);
        }
        for (int i = tid; i < 1024; i += 256) {
            int kt = i >> 6, c = i & 63;
            Bs[kt * 64 + c] = B[(size_t)(k0 + kt) * LIN2 + bnb * 64 + c];
        }
        __syncthreads();
        #pragma unroll
        for (int kt = 0; kt < 16; ++kt) {
            const float4 av = *(const float4*)&As[kt * 72 + ty4];
            const float4 bv = *(const float4*)&Bs[kt * 64 + tx4];
            ACC16(av, bv);
        }
        __syncthreads();
    }
    const int b = bm * 64 + ty4, c = bnb * 64 + tx4;
    #pragma unroll
    for (int i = 0; i < 4; ++i)
        #pragma unroll
        for (int j = 0; j < 4; ++j)
            atomicAdd(&C[(size_t)(b + i) * LIN2 + c + j], acc[i][j]);
}

// ---------------------------------------------------------------------------
// Final: logits = relu(bn2(H2)) @ Wh3 + bh3, softmax. 64 blocks x 32 rows,
// 8 lanes/row, coalesced interleaved float4, shfl_xor(width 8) reduction.
// ---------------------------------------------------------------------------
__global__ __launch_bounds__(256) void final_kernel(
    const float* __restrict__ H2, const float* __restrict__ Wh3,
    const float* __restrict__ bh3, float* __restrict__ out,
    const float* __restrict__ Sg2, const float* __restrict__ S2g2,
    const float* __restrict__ g2, const float* __restrict__ be2)
{
    __shared__ float Ws[LIN2 * NCLS];
    __shared__ float bs[NCLS];
    __shared__ float sc2[LIN2], sh2[LIN2];
    const int tid = threadIdx.x;
    for (int i = tid; i < LIN2 * NCLS; i += 256) Ws[i] = Wh3[i];
    if (tid < NCLS) bs[tid] = bh3[tid];
    {
        float mn  = Sg2[tid] * (1.f / BATCH);
        float var = S2g2[tid] * (1.f / BATCH) - mn * mn;
        float sc  = g2[tid] * rsqrtf(var + BN_EPS);
        sc2[tid] = sc;
        sh2[tid] = be2[tid] - mn * sc;
    }
    __syncthreads();
    const int r     = blockIdx.x * 32 + (tid >> 3);
    const int lane8 = tid & 7;
    float a0 = (lane8 == 0) ? bs[0] : 0.f;
    float a1 = (lane8 == 0) ? bs[1] : 0.f;
    float a2 = (lane8 == 0) ? bs[2] : 0.f;
    const float4* row = (const float4*)&H2[(size_t)r * LIN2];
    #pragma unroll
    for (int i = 0; i < 8; ++i) {
        const int k4 = lane8 + i * 8;
        float4 h = row[k4];
        const int k = k4 * 4;
        float h0 = fmaxf(fmaf(h.x, sc2[k + 0], sh2[k + 0]), 0.f);
        float h1 = fmaxf(fmaf(h.y, sc2[k + 1], sh2[k + 1]), 0.f);
        float h2v = fmaxf(fmaf(h.z, sc2[k + 2], sh2[k + 2]), 0.f);
        float h3 = fmaxf(fmaf(h.w, sc2[k + 3], sh2[k + 3]), 0.f);
        a0 = fmaf(h0, Ws[(k + 0) * 3 + 0], a0);
        a1 = fmaf(h0, Ws[(k + 0) * 3 + 1], a1);
        a2 = fmaf(h0, Ws[(k + 0) * 3 + 2], a2);
        a0 = fmaf(h1, Ws[(k + 1) * 3 + 0], a0);
        a1 = fmaf(h1, Ws[(k + 1) * 3 + 1], a1);
        a2 = fmaf(h1, Ws[(k + 1) * 3 + 2], a2);
        a0 = fmaf(h2v, Ws[(k + 2) * 3 + 0], a0);
        a1 = fmaf(h2v, Ws[(k + 2) * 3 + 1], a1);
        a2 = fmaf(h2v, Ws[(k + 2) * 3 + 2], a2);
        a0 = fmaf(h3, Ws[(k + 3) * 3 + 0], a0);
        a1 = fmaf(h3, Ws[(k + 3) * 3 + 1], a1);
        a2 = fmaf(h3, Ws[(k + 3) * 3 + 2], a2);
    }
    #pragma unroll
    for (int m = 1; m < 8; m <<= 1) {
        a0 += __shfl_xor(a0, m);
        a1 += __shfl_xor(a1, m);
        a2 += __shfl_xor(a2, m);
    }
    if (lane8 == 0) {
        float mx = fmaxf(a0, fmaxf(a1, a2));
        float e0 = expf(a0 - mx), e1 = expf(a1 - mx), e2 = expf(a2 - mx);
        float inv = 1.f / (e0 + e1 + e2);
        out[r * 3 + 0] = e0 * inv;
        out[r * 3 + 1] = e1 * inv;
        out[r * 3 + 2] = e2 * inv;
    }
}

// ---------------------------------------------------------------------------
extern "C" void kernel_launch(void* const* d_in, const int* in_sizes, int n_in,
                              void* d_out, int out_size, void* d_ws, size_t ws_size,
                              hipStream_t stream)
{
    const float* x   = (const float*)d_in[0];
    const int*   ei  = (const int*)  d_in[1];
    const float* W1  = (const float*)d_in[2];
    const float* b1  = (const float*)d_in[3];
    const float* W2  = (const float*)d_in[4];
    const float* b2  = (const float*)d_in[5];
    const float* W3  = (const float*)d_in[6];
    const float* b3  = (const float*)d_in[7];
    const float* W4  = (const float*)d_in[8];
    const float* b4  = (const float*)d_in[9];
    const float* Wh1 = (const float*)d_in[10];
    const float* bh1 = (const float*)d_in[11];
    const float* g1  = (const float*)d_in[12];
    const float* be1 = (const float*)d_in[13];
    const float* Wh2 = (const float*)d_in[14];
    const float* bh2 = (const float*)d_in[15];
    const float* g2  = (const float*)d_in[16];
    const float* be2 = (const float*)d_in[17];
    const float* Wh3 = (const float*)d_in[18];
    const float* bh3 = (const float*)d_in[19];
    float* out = (float*)d_out;

    // workspace layout -- TOTAL ~148.7 MB (R10/R14-proven offsets).
    // BN stats scratch in the previously-unused first 32KB.
    char* ws = (char*)d_ws;
    float* Sg1  = (float*)(ws + 0);      // 512 f
    float* S2g1 = (float*)(ws + 2048);   // 512 f
    float* Sg2  = (float*)(ws + 4096);   // 256 f
    float* S2g2 = (float*)(ws + 5120);   // 256 f (zeroed region: ws+0..8192)
    unsigned short* Tf    = (unsigned short*)(ws + 32768);           // 32768
    unsigned short* WTall = (unsigned short*)(ws + 65536);           // 688128
    unsigned short* Wh1T  = (unsigned short*)(ws + 753664);          // 15,745,024
    float* X248 = (float*)(ws + 16498688);                           // 125,960,192
    float* H1   = (float*)(ws + 142458880);                          // 4,194,304
    float* H2   = (float*)(ws + 146653184);                          // 2,097,152

    const int E   = in_sizes[1] / 2;   // 1,015,808
    const int epg = E / BATCH;         // 496 edges of graph 0

    prep_kernel<<<PREP_GRID, 256, 0, stream>>>(
        ei, E, epg, Tf, W1, W2, W3, W4, WTall, Wh1, Wh1T, H1, bh1, H2, bh2,
        (float*)ws);

    cheb_mfma<<<BATCH, 256, 0, stream>>>(x, X248, WTall + (size_t)0 * 12288,  Tf, b1, 128, 128);
    cheb_mfma<<<BATCH, 256, 0, stream>>>(x, X248, WTall + (size_t)4 * 12288,  Tf, b2, 190, 192);
    cheb_mfma<<<BATCH, 256, 0, stream>>>(x, X248, WTall + (size_t)10 * 12288, Tf, b3, 252, 256);
    cheb_mfma<<<BATCH, 256, 0, stream>>>(x, X248, WTall + (size_t)18 * 12288, Tf, b4, 314, 320);

    gemm_head1_mfma<<<dim3(32, 4, SPLIT1), 256, 0, stream>>>(X248, Wh1T, H1);

    bn_stats<<<dim3(LIN1 / 16, 16), 256, 0, stream>>>(H1, LIN1, Sg1, S2g1);
    gemm2_kernel<<<dim3(32, 4, SPLIT2), 256, 0, stream>>>(H1, Wh2, H2, Sg1, S2g1, g1, be1);
    bn_stats<<<dim3(LIN2 / 16, 16), 256, 0, stream>>>(H2, LIN2, Sg2, S2g2);
    final_kernel<<<BATCH / 32, 256, 0, stream>>>(H2, Wh3, bh3, out, Sg2, S2g2, g2, be2);
}